// Round 30
// baseline (119.086 us; speedup 1.0000x reference)
//
#include <hip/hip_runtime.h>

#define K_CODES 1024
#define DIMS    256
#define NROWS   32768   // B*H*W = 32*32*32

typedef __attribute__((ext_vector_type(8)))  short bf16x8;
typedef __attribute__((ext_vector_type(16))) float f32x16;

// NOTE (R16 lesson): never gate host launch logic on __has_builtin of device
// builtins (host pass sees 0). mfma_f32_32x32x16_bf16 verified on gfx950.

// ---------------- MFMA-path ws layout (float units), ~2.0 MB ----------------
#define WS_BH    0                             // 262144 ushort = 131072 floats
#define WS_ESQ   (WS_BH + 131072)
#define WS_CAND  (WS_ESQ + K_CODES)            // int4 per row x 2 halves
#define WS_XP    (WS_CAND + NROWS * 8)         // 3 x NROWS partial sums
#define WS_MFMA_NEED_FLOATS (WS_XP + 3 * NROWS)
#define WS_MFMA_NEED_BYTES  ((size_t)WS_MFMA_NEED_FLOATS * 4)

// fp32 fallback layout (R12 verified)
#define F32_ET    0
#define F32_ESQ   (F32_ET  + DIMS * K_CODES)
#define F32_XSQ   (F32_ESQ + K_CODES)
#define F32_CAND  (F32_XSQ + NROWS)
#define F32_NEED_FLOATS (F32_CAND + 4 * NROWS * 2)
#define F32_NEED_BYTES  ((size_t)F32_NEED_FLOATS * 4)

// ---------------------------------------------------------------------------
// numpy-bitwise sum of squares of a 256-element row (verified round 2).
// ---------------------------------------------------------------------------
__device__ __forceinline__ float sq_at(const float* p, int d, int stride) {
#pragma clang fp contract(off)
    const float v = p[(size_t)d * stride];
    return v * v;
}

__device__ __forceinline__ float np_block_sq(const float* p, int stride, int o, int n) {
#pragma clang fp contract(off)
    float r[8];
    #pragma unroll
    for (int k = 0; k < 8; ++k) r[k] = sq_at(p, o + k, stride);
    const int n8 = n - (n % 8);
    for (int i = 8; i < n8; i += 8) {
        #pragma unroll
        for (int k = 0; k < 8; ++k) r[k] = r[k] + sq_at(p, o + i + k, stride);
    }
    float res = ((r[0] + r[1]) + (r[2] + r[3])) + ((r[4] + r[5]) + (r[6] + r[7]));
    for (int i = n8; i < n; ++i) res = res + sq_at(p, o + i, stride);
    return res;
}

__device__ __forceinline__ float np_sumsq_row(const float* p, int stride) {
#pragma clang fp contract(off)
    const float p120 = np_block_sq(p, stride, 1,   120);
    const float p64  = np_block_sq(p, stride, 121, 64);
    const float p71  = np_block_sq(p, stride, 185, 71);
    const float s135 = p64 + p71;
    const float s255 = p120 + s135;
    return sq_at(p, 0, stride) + s255;
}

// bf16 round-to-nearest-even (same helper for A and B packs: consistency)
__device__ __forceinline__ unsigned short f32_to_bf16_rne(float f) {
    unsigned u = __float_as_uint(f);
    u += 0x7fffu + ((u >> 16) & 1u);
    return (unsigned short)(u >> 16);
}

// ---------------- prologue: esq(4) | B-pack32(1024) | xsq-pieces(384) -------
// B-pack for 32x32x16: layout [kc][tile][lane][i]; code c = tile*32+(ln&31),
// k = kc*16 + (ln>>5)*8 + i. A uses the SAME slot->k bijection -> correctness
// independent of the hardware's internal k ordering (R17-verified argument).
__global__ void vq_prologue_mfma(const float* __restrict__ x, const float* __restrict__ cb,
                                 float* __restrict__ esq, unsigned short* __restrict__ bh,
                                 float* __restrict__ xp) {
    const int bid = blockIdx.x;
    if (bid < 4) {                                     // esq (np-exact)
        const int c = bid * 256 + threadIdx.x;
        esq[c] = np_sumsq_row(cb + (size_t)c * DIMS, 1);
    } else if (bid < 1028) {                           // bf16 B pack (32x32 layout)
        const int idx = (bid - 4) * 256 + threadIdx.x;     // 0..262143
        const int i    = idx & 7;
        const int ln   = (idx >> 3) & 63;
        const int tile = (idx >> 9) & 31;
        const int kc   = idx >> 14;                    // 0..15
        const int c = tile * 32 + (ln & 31);
        const int k = kc * 16 + (ln >> 5) * 8 + i;
        bh[idx] = f32_to_bf16_rne(cb[(size_t)c * DIMS + k]);
    } else {                                           // xsq pieces (3 x 128 blk)
        const int bid2  = bid - 1028;
        const int piece = bid2 / 128;                  // 0..2
        const int n     = (bid2 % 128) * 256 + threadIdx.x;
        const float* p  = x + ((size_t)(n >> 10)) * (DIMS * 1024) + (n & 1023);
        const int o   = (piece == 0) ? 1   : (piece == 1) ? 121 : 185;
        const int len = (piece == 0) ? 120 : (piece == 1) ? 64  : 71;
        xp[(size_t)piece * NROWS + n] = np_block_sq(p, 1024, o, len);
    }
}

// ---------------- MFMA filter: 32x32x16 shape, half-split, 32 rows/wave -----
// R29 post-mortem: 16x16 + quarter-split doubled x-fetch (66MB) -> revert to
// half-split (x-traffic = R28's) and get LDS efficiency from the SHAPE:
// 32x32x16 consumes 16B/lane of B per 16384 MACs (2x the 16x16 rate) and
// 32 rows/wave doubles reuse again -> LDS reads/CU 8.4MB -> 2.1MB (~10us).
// Wave = 32 rows x 512 codes (16 tiles of 32); block = 4 waves; grid 512.
// C/D map (m74/m101-verified): col=lane&31, row=(reg&3)+8*(reg>>2)+4*(lane>>5).
// Per-lane top-2 over its column's 16 codes; 3-extraction lexmin over the
// 32-lane group -> 3 candidates per (row, half) -> refine = R28 byte-exact.
__global__ __launch_bounds__(256, 2)
void vq_mfma_filter(const float* __restrict__ x, const unsigned short* __restrict__ bh,
                    const float* __restrict__ esq, int4* __restrict__ cand) {
    __shared__ int4 lbh[2][1024];  // 2 x 16 KB tile buffers

    const int tid  = (int)threadIdx.x;
    const int wid  = __builtin_amdgcn_readfirstlane(tid >> 6);
    const int lane = tid & 63;
    const int h      = blockIdx.x & 1;                 // codebook half
    const int rowblk = (blockIdx.x >> 1) * 4 + wid;    // 0..1023
    const int row0 = rowblk * 32;                      // 32 | 1024 -> one image
    const int b  = row0 >> 10;
    const int hw = (row0 & 1023) + (lane & 31);        // A: m = lane&31
    const float* xb = x + (size_t)b * (DIMS * 1024) + hw;
    const int tile0 = h * 16;                          // first tile of half

    // A fragments: A[m = lane&31][k = kc*16 + (lane>>5)*8 + i]
    bf16x8 afr[16];
    #pragma unroll
    for (int kc = 0; kc < 16; ++kc) {
        #pragma unroll
        for (int i = 0; i < 8; ++i) {
            const int k = kc * 16 + (lane >> 5) * 8 + i;
            afr[kc][i] = (short)f32_to_bf16_rne(xb[(size_t)k * 1024]);
        }
    }

    // per-lane top-2 per reg-row (16 rows/lane), code = tile*32 + (lane&31)
    float lv[16][2]; int lc[16][2];
    #pragma unroll
    for (int r = 0; r < 16; ++r) {
        lv[r][0] = 3.4e38f; lv[r][1] = 3.4e38f;
        lc[r][0] = 0x7fffffff; lc[r][1] = 0x7fffffff;
    }

    const int4* bh4 = reinterpret_cast<const int4*>(bh);

    // stage one tile: 16 kc x 64 lanes x 16B (coalesced, 16B/lane)
#define STAGE(BUF, TILE)                                                       \
    do {                                                                       \
        _Pragma("unroll")                                                      \
        for (int e = 0; e < 4; ++e) {                                          \
            const int idx = e * 256 + tid;             /* 0..1023 */           \
            const int ln_ = idx & 63;                                          \
            const int kc_ = idx >> 6;                  /* 0..15 */             \
            lbh[BUF][idx] = bh4[(kc_ * 32 + (TILE)) * 64 + ln_];               \
        }                                                                      \
    } while (0)

    STAGE(0, tile0);
    __syncthreads();
    for (int t = 0; t < 16; ++t) {
        const int cur = t & 1;
        if (t + 1 < 16) STAGE(cur ^ 1, tile0 + t + 1);   // prefetch next tile

        f32x16 acc = {0.f, 0.f, 0.f, 0.f, 0.f, 0.f, 0.f, 0.f,
                      0.f, 0.f, 0.f, 0.f, 0.f, 0.f, 0.f, 0.f};
        #pragma unroll
        for (int kc = 0; kc < 16; ++kc) {
            const int li = kc * 64 + lane;               // 16B/lane: 2-way free
            acc = __builtin_amdgcn_mfma_f32_32x32x16_bf16(
                afr[kc], *reinterpret_cast<const bf16x8*>(&lbh[cur][li]), acc, 0, 0, 0);
        }
        const int   c  = (tile0 + t) * 32 + (lane & 31);
        const float es = esq[c];
        #pragma unroll
        for (int r = 0; r < 16; ++r) {
            // x_sq omitted: constant per row -> ordering-invariant for filter
            const float v = fmaf(-2.0f, acc[r], es);
            if (v < lv[r][0]) { lv[r][1] = lv[r][0]; lc[r][1] = lc[r][0]; lv[r][0] = v; lc[r][0] = c; }
            else if (v < lv[r][1]) { lv[r][1] = v; lc[r][1] = c; }
        }
        __syncthreads();   // next-tile staging done AND this tile's reads done
    }
#undef STAGE

    // per-row merge: 3 lexmin extractions over the 32-lane group
    // (shfl_xor offs 1..16 stay within the lane<32 / lane>=32 group; all
    //  lanes of a group hold the SAME row at reg r)
    #pragma unroll
    for (int r = 0; r < 16; ++r) {
        float a1v = lv[r][0]; int a1c = lc[r][0];
        float a2v = lv[r][1]; int a2c = lc[r][1];
        int c3[3];
        #pragma unroll
        for (int e = 0; e < 3; ++e) {
            float mv = a1v; int mc = a1c;
            #pragma unroll
            for (int off = 1; off < 32; off <<= 1) {
                const float ov = __shfl_xor(mv, off, 64);
                const int   oc = __shfl_xor(mc, off, 64);
                if (ov < mv || (ov == mv && oc < mc)) { mv = ov; mc = oc; }
            }
            c3[e] = mc;
            if (a1c == mc) { a1v = a2v; a1c = a2c; a2v = 3.4e38f; a2c = 0x7fffffff; }  // pop owner
        }
        if ((lane & 31) == 0) {
            const int R = row0 + (r & 3) + 8 * (r >> 2) + 4 * (lane >> 5);
            cand[(size_t)h * NROWS + R] = make_int4(c3[0], c3[1], c3[2], 0);
        }
    }
}

// ---------------- fused refine+reduce (BYTE-EXACT R28) ----------------------
__global__ __launch_bounds__(192, 2)
void vq_refine_fused(const float* __restrict__ x, const float* __restrict__ cb,
                     const float* __restrict__ esq, const int4* __restrict__ cand,
                     const float* __restrict__ xp, int* __restrict__ out) {
    __shared__ float sacc[6][32];
    __shared__ int   scc[6][32];

    const int t    = (int)threadIdx.x;
    const int r    = t & 31;               // row in block
    const int slot = t >> 5;               // 0..5
    const int n  = blockIdx.x * 32 + r;
    const int b  = n >> 10;
    const int hw = n & 1023;
    const float* xr = x + (size_t)b * (DIMS * 1024) + hw;

    const int4 cd = cand[(size_t)(slot / 3) * NROWS + n];
    const int k3 = slot % 3;
    const int cc = (k3 == 0) ? cd.x : (k3 == 1) ? cd.y : cd.z;

    float acc = 0.f;
    for (int d0 = 0; d0 < DIMS; d0 += 32) {
        float xv[32];
        #pragma unroll
        for (int i = 0; i < 32; ++i) xv[i] = xr[(size_t)(d0 + i) * 1024];
        const float4* ec4 = reinterpret_cast<const float4*>(cb + (size_t)cc * DIMS + d0);
        #pragma unroll
        for (int q = 0; q < 8; ++q) {
            const float4 e = ec4[q];
            acc = fmaf(xv[q * 4 + 0], e.x, acc);
            acc = fmaf(xv[q * 4 + 1], e.y, acc);
            acc = fmaf(xv[q * 4 + 2], e.z, acc);
            acc = fmaf(xv[q * 4 + 3], e.w, acc);
        }
    }
    sacc[slot][r] = acc;
    scc[slot][r]  = cc;
    __syncthreads();
    if (t < 32) {
#pragma clang fp contract(off)
        const int n2  = blockIdx.x * 32 + t;
        const float x0 = x[(size_t)(n2 >> 10) * (DIMS * 1024) + (n2 & 1023)];   // d=0
        const float q0 = x0 * x0;
        const float p120 = xp[n2];
        const float p64  = xp[NROWS + n2];
        const float p71  = xp[2 * NROWS + n2];
        const float s135 = p64 + p71;
        const float s255 = p120 + s135;
        const float xs   = q0 + s255;
        float bestv = 3.4e38f; int bestc = 0x7fffffff;
        #pragma unroll
        for (int k = 0; k < 6; ++k) {
            const float t3 = xs - 2.0f * sacc[k][t];
            const float v  = t3 + esq[scc[k][t]];
            if (v < bestv || (v == bestv && scc[k][t] < bestc)) { bestv = v; bestc = scc[k][t]; }
        }
        out[n2] = bestc;
    }
}

// ===========================================================================
// fp32 fallback path — R12 verified (prologue + v7 main + reduce, 236us).
// Only used if ws_size < 2.0MB (never observed; kept for safety).
// ===========================================================================
__global__ void vq_prologue_f32(const float* __restrict__ x, const float* __restrict__ cb,
                                float* __restrict__ xsq, float* __restrict__ esq,
                                float4* __restrict__ et4) {
    const int bid = blockIdx.x;
    if (bid < 128) {
        const int n = bid * 256 + threadIdx.x;
        const float* p = x + ((size_t)(n >> 10)) * (DIMS * 1024) + (n & 1023);
        xsq[n] = np_sumsq_row(p, 1024);
    } else if (bid < 132) {
        const int c = (bid - 128) * 256 + threadIdx.x;
        esq[c] = np_sumsq_row(cb + (size_t)c * DIMS, 1);
    } else {
        const int idx = (bid - 132) * 256 + threadIdx.x;
        const int dk  = idx & 63;
        const int c   = idx >> 6;
        const float4 v = *reinterpret_cast<const float4*>(cb + (size_t)c * DIMS + dk * 4);
        et4[(size_t)dk * K_CODES + c] = v;
    }
}

__global__ __launch_bounds__(256, 2)
void vq_main7_kernel(const float* __restrict__ x, const float4* __restrict__ et4,
                     const float* __restrict__ esq, const float* __restrict__ xsq,
                     float2* __restrict__ cand) {
    const int wid  = __builtin_amdgcn_readfirstlane((int)(threadIdx.x >> 6));
    const int lane = threadIdx.x & 63;
    const int W     = blockIdx.x * 4 + wid;
    const int g     = W & 3;
    const int slice = W >> 2;
    const int c0    = g * 256 + lane;
    const int row_base = slice * 8;
    const int b    = row_base >> 10;
    const int hw0  = row_base & 1023;
    const float* xb = x + (size_t)b * (DIMS * 1024) + hw0;

    const float esq0 = esq[c0];
    const float esq1 = esq[c0 + 64];
    const float esq2 = esq[c0 + 128];
    const float esq3 = esq[c0 + 192];

    float acc0[8], acc1[8], acc2[8], acc3[8];
    #pragma unroll
    for (int r = 0; r < 8; ++r) { acc0[r] = 0.0f; acc1[r] = 0.0f; acc2[r] = 0.0f; acc3[r] = 0.0f; }

    for (int dk = 0; dk < DIMS / 4; ++dk) {
        const float4* ep = et4 + (size_t)dk * K_CODES;
        const float4 e0 = ep[c0];
        const float4 e1 = ep[c0 + 64];
        const float4 e2 = ep[c0 + 128];
        const float4 e3 = ep[c0 + 192];

        #pragma unroll
        for (int dd = 0; dd < 4; ++dd) {
            float xv[8];
            #pragma unroll
            for (int r = 0; r < 8; ++r)
                xv[r] = xb[(size_t)(dk * 4 + dd) * 1024 + r];
            const float ev0 = (dd == 0) ? e0.x : (dd == 1) ? e0.y : (dd == 2) ? e0.z : e0.w;
            const float ev1 = (dd == 0) ? e1.x : (dd == 1) ? e1.y : (dd == 2) ? e1.z : e1.w;
            const float ev2 = (dd == 0) ? e2.x : (dd == 1) ? e2.y : (dd == 2) ? e2.z : e2.w;
            const float ev3 = (dd == 0) ? e3.x : (dd == 1) ? e3.y : (dd == 2) ? e3.z : e3.w;
            #pragma unroll
            for (int r = 0; r < 8; ++r) acc0[r] = fmaf(xv[r], ev0, acc0[r]);
            #pragma unroll
            for (int r = 0; r < 8; ++r) acc1[r] = fmaf(xv[r], ev1, acc1[r]);
            #pragma unroll
            for (int r = 0; r < 8; ++r) acc2[r] = fmaf(xv[r], ev2, acc2[r]);
            #pragma unroll
            for (int r = 0; r < 8; ++r) acc3[r] = fmaf(xv[r], ev3, acc3[r]);
        }
    }

    {
#pragma clang fp contract(off)
        float keepv = 0.0f; int keepc = 0;
        #pragma unroll
        for (int r = 0; r < 8; ++r) {
            const float xs_r = xsq[row_base + r];
            const float v0 = (xs_r - 2.0f * acc0[r]) + esq0;
            const float v1 = (xs_r - 2.0f * acc1[r]) + esq1;
            const float v2 = (xs_r - 2.0f * acc2[r]) + esq2;
            const float v3 = (xs_r - 2.0f * acc3[r]) + esq3;
            float bv = v0; int bc = c0;
            if (v1 < bv) { bv = v1; bc = c0 + 64; }
            if (v2 < bv) { bv = v2; bc = c0 + 128; }
            if (v3 < bv) { bv = v3; bc = c0 + 192; }
            #pragma unroll
            for (int off = 1; off < 64; off <<= 1) {
                const float ov = __shfl_xor(bv, off, 64);
                const int   oc = __shfl_xor(bc, off, 64);
                if (ov < bv || (ov == bv && oc < bc)) { bv = ov; bc = oc; }
            }
            if (lane == r) { keepv = bv; keepc = bc; }
        }
        if (lane < 8) {
            cand[(size_t)g * NROWS + row_base + lane] =
                make_float2(keepv, __int_as_float(keepc));
        }
    }
}

__global__ void vq_reduce_kernel(const float2* __restrict__ cand, int* __restrict__ out) {
    const int row = blockIdx.x * 256 + threadIdx.x;
    float2 p = cand[row];
    float bv = p.x; int bc = __float_as_int(p.y);
    #pragma unroll
    for (int gg = 1; gg < 4; ++gg) {
        const float2 q = cand[(size_t)gg * NROWS + row];
        const float v = q.x; const int qc = __float_as_int(q.y);
        if (v < bv || (v == bv && qc < bc)) { bv = v; bc = qc; }
    }
    out[row] = bc;
}

// ===========================================================================
extern "C" void kernel_launch(void* const* d_in, const int* in_sizes, int n_in,
                              void* d_out, int out_size, void* d_ws, size_t ws_size,
                              hipStream_t stream) {
    const float* x  = (const float*)d_in[0];   // [32, 256, 32, 32]
    const float* cb = (const float*)d_in[1];   // [1024, 256]
    int* out = (int*)d_out;                    // [32768] int32
    float* ws = (float*)d_ws;

    if (ws_size >= WS_MFMA_NEED_BYTES) {
        unsigned short* bh = (unsigned short*)(ws + WS_BH);
        float* esq = ws + WS_ESQ;
        int4*  cnd = (int4*)(ws + WS_CAND);
        float* xp  = ws + WS_XP;

        vq_prologue_mfma<<<4 + 1024 + 384, 256, 0, stream>>>(x, cb, esq, bh, xp);
        vq_mfma_filter<<<512, 256, 0, stream>>>(x, bh, esq, cnd);
        vq_refine_fused<<<NROWS / 32, 192, 0, stream>>>(x, cb, esq, cnd, xp, out);
        return;
    }
    // fp32 fallback (R12, verified 236us)
    {
        float4* et4  = (float4*)(ws + F32_ET);
        float*  esq  = ws + F32_ESQ;
        float*  xsq  = ws + F32_XSQ;
        float2* cand = (float2*)(ws + F32_CAND);

        vq_prologue_f32<<<128 + 4 + 256, 256, 0, stream>>>(x, cb, xsq, esq, et4);
        vq_main7_kernel<<<(NROWS / 8) * 4 / 4, 256, 0, stream>>>(x, et4, esq, xsq, cand);
        vq_reduce_kernel<<<NROWS / 256, 256, 0, stream>>>(cand, out);
    }
}

// Round 31
// 95.185 us; speedup vs baseline: 1.2511x; 1.2511x over previous
//
#include <hip/hip_runtime.h>

#define K_CODES 1024
#define DIMS    256
#define NROWS   32768   // B*H*W = 32*32*32

typedef __attribute__((ext_vector_type(8))) short bf16x8;
typedef __attribute__((ext_vector_type(4))) float f32x4;

// NOTE (R16 lesson): never gate host launch logic on __has_builtin of device
// builtins (host pass sees 0). mfma_f32_16x16x32_bf16 verified on gfx950.
//
// R31: byte-exact restore of the R28 configuration (measured best: 96.3us).
// Filter design space fully measured: 16x16/half-split/4-wave/dbuf = 44.5us
// (93% of its 41us LDS-pipe floor); all alternatives regressed (2-wave=53,
// quarter-split=54, 2-row-groups=81, 32x32-shape=67).

// ---------------- MFMA-path ws layout (float units), ~2.0 MB ----------------
#define WS_BH    0                             // 262144 ushort = 131072 floats
#define WS_ESQ   (WS_BH + 131072)
#define WS_CAND  (WS_ESQ + K_CODES)            // int4 per row x 2 halves
#define WS_XP    (WS_CAND + NROWS * 8)         // 3 x NROWS partial sums
#define WS_MFMA_NEED_FLOATS (WS_XP + 3 * NROWS)
#define WS_MFMA_NEED_BYTES  ((size_t)WS_MFMA_NEED_FLOATS * 4)

// fp32 fallback layout (R12 verified)
#define F32_ET    0
#define F32_ESQ   (F32_ET  + DIMS * K_CODES)
#define F32_XSQ   (F32_ESQ + K_CODES)
#define F32_CAND  (F32_XSQ + NROWS)
#define F32_NEED_FLOATS (F32_CAND + 4 * NROWS * 2)
#define F32_NEED_BYTES  ((size_t)F32_NEED_FLOATS * 4)

// ---------------------------------------------------------------------------
// numpy-bitwise sum of squares of a 256-element row (verified round 2).
// np_sumsq_row(p) == sq(p[0]) + (P(1,120) + (P(121,64) + P(185,71))) where
// P = np_block_sq — the three P pieces are INDEPENDENT (exploited since R28).
// ---------------------------------------------------------------------------
__device__ __forceinline__ float sq_at(const float* p, int d, int stride) {
#pragma clang fp contract(off)
    const float v = p[(size_t)d * stride];
    return v * v;
}

__device__ __forceinline__ float np_block_sq(const float* p, int stride, int o, int n) {
#pragma clang fp contract(off)
    float r[8];
    #pragma unroll
    for (int k = 0; k < 8; ++k) r[k] = sq_at(p, o + k, stride);
    const int n8 = n - (n % 8);
    for (int i = 8; i < n8; i += 8) {
        #pragma unroll
        for (int k = 0; k < 8; ++k) r[k] = r[k] + sq_at(p, o + i + k, stride);
    }
    float res = ((r[0] + r[1]) + (r[2] + r[3])) + ((r[4] + r[5]) + (r[6] + r[7]));
    for (int i = n8; i < n; ++i) res = res + sq_at(p, o + i, stride);
    return res;
}

__device__ __forceinline__ float np_sumsq_row(const float* p, int stride) {
#pragma clang fp contract(off)
    const float p120 = np_block_sq(p, stride, 1,   120);
    const float p64  = np_block_sq(p, stride, 121, 64);
    const float p71  = np_block_sq(p, stride, 185, 71);
    const float s135 = p64 + p71;
    const float s255 = p120 + s135;
    return sq_at(p, 0, stride) + s255;
}

// bf16 round-to-nearest-even (same helper for A and B packs: consistency)
__device__ __forceinline__ unsigned short f32_to_bf16_rne(float f) {
    unsigned u = __float_as_uint(f);
    u += 0x7fffu + ((u >> 16) & 1u);
    return (unsigned short)(u >> 16);
}

// ---------------- prologue: esq(4) | B-pack(1024) | xsq-pieces(384) ---------
__global__ void vq_prologue_mfma(const float* __restrict__ x, const float* __restrict__ cb,
                                 float* __restrict__ esq, unsigned short* __restrict__ bh,
                                 float* __restrict__ xp) {
    const int bid = blockIdx.x;
    if (bid < 4) {                                     // esq (np-exact)
        const int c = bid * 256 + threadIdx.x;
        esq[c] = np_sumsq_row(cb + (size_t)c * DIMS, 1);
    } else if (bid < 1028) {                           // bf16 B pack (hi plane)
        const int idx = (bid - 4) * 256 + threadIdx.x;     // 0..262143
        const int i  = idx & 7;
        const int ln = (idx >> 3) & 63;
        const int t  = (idx >> 9) & 63;
        const int kc = idx >> 15;
        const int c  = t * 16 + (ln & 15);
        const int k  = kc * 32 + (ln >> 4) * 8 + i;
        bh[idx] = f32_to_bf16_rne(cb[(size_t)c * DIMS + k]);
    } else {                                           // xsq pieces (3 x 128 blk)
        const int bid2  = bid - 1028;
        const int piece = bid2 / 128;                  // 0..2
        const int n     = (bid2 % 128) * 256 + threadIdx.x;
        const float* p  = x + ((size_t)(n >> 10)) * (DIMS * 1024) + (n & 1023);
        const int o   = (piece == 0) ? 1   : (piece == 1) ? 121 : 185;
        const int len = (piece == 0) ? 120 : (piece == 1) ? 64  : 71;
        xp[(size_t)piece * NROWS + n] = np_block_sq(p, 1024, o, len);
    }
}

// ---------------- MFMA filter: BYTE-EXACT R23/R28 (best measured: 44.5us) ---
// 4-wave blocks, codebook split across 2 blocks (grid 1024 = 4 blocks/CU),
// LDS double-buffered 16KB chunks.
__global__ __launch_bounds__(256, 2)
void vq_mfma_filter(const float* __restrict__ x, const unsigned short* __restrict__ bh,
                    const float* __restrict__ esq, int4* __restrict__ cand) {
    __shared__ int4 lbh[2][1024];  // 2 x 16 KB chunk buffers (2 tiles each)

    const int tid  = (int)threadIdx.x;
    const int wid  = __builtin_amdgcn_readfirstlane(tid >> 6);
    const int lane = tid & 63;
    const int h      = blockIdx.x & 1;             // codebook half
    const int rowblk = (blockIdx.x >> 1) * 4 + wid;    // 0..2047
    const int row0 = rowblk * 16;                  // 16 | 1024 -> one image
    const int b  = row0 >> 10;
    const int hw = (row0 & 1023) + (lane & 15);
    const float* xb = x + (size_t)b * (DIMS * 1024) + hw;
    const int g = lane >> 4;
    const int tile0 = h * 32;                      // first code-tile of half

    // A fragments: A[m = lane&15][k = kc*32 + g*8 + i], bf16 RNE on the fly
    bf16x8 afr[8];
    #pragma unroll
    for (int kc = 0; kc < 8; ++kc) {
        #pragma unroll
        for (int i = 0; i < 8; ++i) {
            const int k = kc * 32 + g * 8 + i;
            afr[kc][i] = (short)f32_to_bf16_rne(xb[(size_t)k * 1024]);
        }
    }

    float lv[4][2]; int lc[4][2];
    #pragma unroll
    for (int j = 0; j < 4; ++j) {
        lv[j][0] = 3.4e38f; lv[j][1] = 3.4e38f;
        lc[j][0] = 0x7fffffff; lc[j][1] = 0x7fffffff;
    }

    const int4* bh4 = reinterpret_cast<const int4*>(bh);

#define STAGE(BUF, CHUNK)                                                      \
    do {                                                                       \
        _Pragma("unroll")                                                      \
        for (int e = 0; e < 4; ++e) {                                          \
            const int idx = e * 256 + tid;             /* 0..1023 */           \
            const int ln_ = idx & 63;                                          \
            const int tt_ = (idx >> 6) & 1;                                    \
            const int kc_ = idx >> 7;                                          \
            lbh[BUF][idx] =                                                    \
                bh4[(kc_ * 64 + tile0 + (CHUNK) * 2 + tt_) * 64 + ln_];        \
        }                                                                      \
    } while (0)

    STAGE(0, 0);
    __syncthreads();
    for (int chunk = 0; chunk < 16; ++chunk) {
        const int cur = chunk & 1;
        if (chunk + 1 < 16) STAGE(cur ^ 1, chunk + 1);   // prefetch next chunk

        #pragma unroll
        for (int tt = 0; tt < 2; ++tt) {
            const int t = tile0 + chunk * 2 + tt;        // global code tile
            f32x4 acch = {0.f, 0.f, 0.f, 0.f};
            #pragma unroll
            for (int kc = 0; kc < 8; ++kc) {
                const int li = (kc * 2 + tt) * 64 + lane;   // 16B/lane: 2-way free
                acch = __builtin_amdgcn_mfma_f32_16x16x32_bf16(
                    afr[kc], *reinterpret_cast<const bf16x8*>(&lbh[cur][li]), acch, 0, 0, 0);
            }
            const int   c  = t * 16 + (lane & 15);
            const float es = esq[c];
            #pragma unroll
            for (int j = 0; j < 4; ++j) {
                // x_sq omitted: constant per row -> ordering-invariant for filter
                const float v = fmaf(-2.0f, acch[j], es);
                if (v < lv[j][0]) { lv[j][1] = lv[j][0]; lc[j][1] = lc[j][0]; lv[j][0] = v; lc[j][0] = c; }
                else if (v < lv[j][1]) { lv[j][1] = v; lc[j][1] = c; }
            }
        }
        __syncthreads();   // next-chunk staging done AND this chunk's reads done
    }
#undef STAGE

    // per-row merge: 3 lexmin extractions over the 16-lane subgroup
    int c3[4][3];
    #pragma unroll
    for (int j = 0; j < 4; ++j) {
        float a1v = lv[j][0]; int a1c = lc[j][0];
        float a2v = lv[j][1]; int a2c = lc[j][1];
        #pragma unroll
        for (int e = 0; e < 3; ++e) {
            float mv = a1v; int mc = a1c;
            #pragma unroll
            for (int off = 1; off < 16; off <<= 1) {
                const float ov = __shfl_xor(mv, off, 16);
                const int   oc = __shfl_xor(mc, off, 16);
                if (ov < mv || (ov == mv && oc < mc)) { mv = ov; mc = oc; }
            }
            c3[j][e] = mc;
            if (a1c == mc) { a1v = a2v; a1c = a2c; a2v = 3.4e38f; a2c = 0x7fffffff; }  // pop owner
        }
    }
    if ((lane & 15) == 0) {
        #pragma unroll
        for (int j = 0; j < 4; ++j)
            cand[(size_t)h * NROWS + row0 + g * 4 + j] =
                make_int4(c3[j][0], c3[j][1], c3[j][2], 0);
    }
}

// ---------------- fused refine+reduce (BYTE-EXACT R28) ----------------------
// Thread (slot = t>>5, r = t&31): ONE exact np-order fp32 dot (sequential
// ascending-d fma, float4 cb loads — the verified bitwise chain). The t<32
// reducer recombines xsq pieces in the EXACT np_sumsq_row order:
// xs = fl(q0 + fl(p120 + fl(p64 + p71))), q0 = fl(x0*x0); then
// v_k = fl(fl(xs - 2*acc_k) + esq[cc_k]) ascending k; lexmin tie -> lower
// code (np first-index semantics).
__global__ __launch_bounds__(192, 2)
void vq_refine_fused(const float* __restrict__ x, const float* __restrict__ cb,
                     const float* __restrict__ esq, const int4* __restrict__ cand,
                     const float* __restrict__ xp, int* __restrict__ out) {
    __shared__ float sacc[6][32];
    __shared__ int   scc[6][32];

    const int t    = (int)threadIdx.x;
    const int r    = t & 31;               // row in block
    const int slot = t >> 5;               // 0..5
    const int n  = blockIdx.x * 32 + r;
    const int b  = n >> 10;
    const int hw = n & 1023;
    const float* xr = x + (size_t)b * (DIMS * 1024) + hw;

    const int4 cd = cand[(size_t)(slot / 3) * NROWS + n];
    const int k3 = slot % 3;
    const int cc = (k3 == 0) ? cd.x : (k3 == 1) ? cd.y : cd.z;

    float acc = 0.f;
    for (int d0 = 0; d0 < DIMS; d0 += 32) {
        float xv[32];
        #pragma unroll
        for (int i = 0; i < 32; ++i) xv[i] = xr[(size_t)(d0 + i) * 1024];
        const float4* ec4 = reinterpret_cast<const float4*>(cb + (size_t)cc * DIMS + d0);
        #pragma unroll
        for (int q = 0; q < 8; ++q) {
            const float4 e = ec4[q];
            acc = fmaf(xv[q * 4 + 0], e.x, acc);
            acc = fmaf(xv[q * 4 + 1], e.y, acc);
            acc = fmaf(xv[q * 4 + 2], e.z, acc);
            acc = fmaf(xv[q * 4 + 3], e.w, acc);
        }
    }
    sacc[slot][r] = acc;
    scc[slot][r]  = cc;
    __syncthreads();
    if (t < 32) {
#pragma clang fp contract(off)
        const int n2  = blockIdx.x * 32 + t;
        const float x0 = x[(size_t)(n2 >> 10) * (DIMS * 1024) + (n2 & 1023)];   // d=0
        const float q0 = x0 * x0;
        const float p120 = xp[n2];
        const float p64  = xp[NROWS + n2];
        const float p71  = xp[2 * NROWS + n2];
        const float s135 = p64 + p71;
        const float s255 = p120 + s135;
        const float xs   = q0 + s255;
        float bestv = 3.4e38f; int bestc = 0x7fffffff;
        #pragma unroll
        for (int k = 0; k < 6; ++k) {
            const float t3 = xs - 2.0f * sacc[k][t];
            const float v  = t3 + esq[scc[k][t]];
            if (v < bestv || (v == bestv && scc[k][t] < bestc)) { bestv = v; bestc = scc[k][t]; }
        }
        out[n2] = bestc;
    }
}

// ===========================================================================
// fp32 fallback path — R12 verified (prologue + v7 main + reduce, 236us).
// Only used if ws_size < 2.0MB (never observed; kept for safety).
// ===========================================================================
__global__ void vq_prologue_f32(const float* __restrict__ x, const float* __restrict__ cb,
                                float* __restrict__ xsq, float* __restrict__ esq,
                                float4* __restrict__ et4) {
    const int bid = blockIdx.x;
    if (bid < 128) {
        const int n = bid * 256 + threadIdx.x;
        const float* p = x + ((size_t)(n >> 10)) * (DIMS * 1024) + (n & 1023);
        xsq[n] = np_sumsq_row(p, 1024);
    } else if (bid < 132) {
        const int c = (bid - 128) * 256 + threadIdx.x;
        esq[c] = np_sumsq_row(cb + (size_t)c * DIMS, 1);
    } else {
        const int idx = (bid - 132) * 256 + threadIdx.x;
        const int dk  = idx & 63;
        const int c   = idx >> 6;
        const float4 v = *reinterpret_cast<const float4*>(cb + (size_t)c * DIMS + dk * 4);
        et4[(size_t)dk * K_CODES + c] = v;
    }
}

__global__ __launch_bounds__(256, 2)
void vq_main7_kernel(const float* __restrict__ x, const float4* __restrict__ et4,
                     const float* __restrict__ esq, const float* __restrict__ xsq,
                     float2* __restrict__ cand) {
    const int wid  = __builtin_amdgcn_readfirstlane((int)(threadIdx.x >> 6));
    const int lane = threadIdx.x & 63;
    const int W     = blockIdx.x * 4 + wid;
    const int g     = W & 3;
    const int slice = W >> 2;
    const int c0    = g * 256 + lane;
    const int row_base = slice * 8;
    const int b    = row_base >> 10;
    const int hw0  = row_base & 1023;
    const float* xb = x + (size_t)b * (DIMS * 1024) + hw0;

    const float esq0 = esq[c0];
    const float esq1 = esq[c0 + 64];
    const float esq2 = esq[c0 + 128];
    const float esq3 = esq[c0 + 192];

    float acc0[8], acc1[8], acc2[8], acc3[8];
    #pragma unroll
    for (int r = 0; r < 8; ++r) { acc0[r] = 0.0f; acc1[r] = 0.0f; acc2[r] = 0.0f; acc3[r] = 0.0f; }

    for (int dk = 0; dk < DIMS / 4; ++dk) {
        const float4* ep = et4 + (size_t)dk * K_CODES;
        const float4 e0 = ep[c0];
        const float4 e1 = ep[c0 + 64];
        const float4 e2 = ep[c0 + 128];
        const float4 e3 = ep[c0 + 192];

        #pragma unroll
        for (int dd = 0; dd < 4; ++dd) {
            float xv[8];
            #pragma unroll
            for (int r = 0; r < 8; ++r)
                xv[r] = xb[(size_t)(dk * 4 + dd) * 1024 + r];
            const float ev0 = (dd == 0) ? e0.x : (dd == 1) ? e0.y : (dd == 2) ? e0.z : e0.w;
            const float ev1 = (dd == 0) ? e1.x : (dd == 1) ? e1.y : (dd == 2) ? e1.z : e1.w;
            const float ev2 = (dd == 0) ? e2.x : (dd == 1) ? e2.y : (dd == 2) ? e2.z : e2.w;
            const float ev3 = (dd == 0) ? e3.x : (dd == 1) ? e3.y : (dd == 2) ? e3.z : e3.w;
            #pragma unroll
            for (int r = 0; r < 8; ++r) acc0[r] = fmaf(xv[r], ev0, acc0[r]);
            #pragma unroll
            for (int r = 0; r < 8; ++r) acc1[r] = fmaf(xv[r], ev1, acc1[r]);
            #pragma unroll
            for (int r = 0; r < 8; ++r) acc2[r] = fmaf(xv[r], ev2, acc2[r]);
            #pragma unroll
            for (int r = 0; r < 8; ++r) acc3[r] = fmaf(xv[r], ev3, acc3[r]);
        }
    }

    {
#pragma clang fp contract(off)
        float keepv = 0.0f; int keepc = 0;
        #pragma unroll
        for (int r = 0; r < 8; ++r) {
            const float xs_r = xsq[row_base + r];
            const float v0 = (xs_r - 2.0f * acc0[r]) + esq0;
            const float v1 = (xs_r - 2.0f * acc1[r]) + esq1;
            const float v2 = (xs_r - 2.0f * acc2[r]) + esq2;
            const float v3 = (xs_r - 2.0f * acc3[r]) + esq3;
            float bv = v0; int bc = c0;
            if (v1 < bv) { bv = v1; bc = c0 + 64; }
            if (v2 < bv) { bv = v2; bc = c0 + 128; }
            if (v3 < bv) { bv = v3; bc = c0 + 192; }
            #pragma unroll
            for (int off = 1; off < 64; off <<= 1) {
                const float ov = __shfl_xor(bv, off, 64);
                const int   oc = __shfl_xor(bc, off, 64);
                if (ov < bv || (ov == bv && oc < bc)) { bv = ov; bc = oc; }
            }
            if (lane == r) { keepv = bv; keepc = bc; }
        }
        if (lane < 8) {
            cand[(size_t)g * NROWS + row_base + lane] =
                make_float2(keepv, __int_as_float(keepc));
        }
    }
}

__global__ void vq_reduce_kernel(const float2* __restrict__ cand, int* __restrict__ out) {
    const int row = blockIdx.x * 256 + threadIdx.x;
    float2 p = cand[row];
    float bv = p.x; int bc = __float_as_int(p.y);
    #pragma unroll
    for (int gg = 1; gg < 4; ++gg) {
        const float2 q = cand[(size_t)gg * NROWS + row];
        const float v = q.x; const int qc = __float_as_int(q.y);
        if (v < bv || (v == bv && qc < bc)) { bv = v; bc = qc; }
    }
    out[row] = bc;
}

// ===========================================================================
extern "C" void kernel_launch(void* const* d_in, const int* in_sizes, int n_in,
                              void* d_out, int out_size, void* d_ws, size_t ws_size,
                              hipStream_t stream) {
    const float* x  = (const float*)d_in[0];   // [32, 256, 32, 32]
    const float* cb = (const float*)d_in[1];   // [1024, 256]
    int* out = (int*)d_out;                    // [32768] int32
    float* ws = (float*)d_ws;

    if (ws_size >= WS_MFMA_NEED_BYTES) {
        unsigned short* bh = (unsigned short*)(ws + WS_BH);
        float* esq = ws + WS_ESQ;
        int4*  cnd = (int4*)(ws + WS_CAND);
        float* xp  = ws + WS_XP;

        vq_prologue_mfma<<<4 + 1024 + 384, 256, 0, stream>>>(x, cb, esq, bh, xp);
        vq_mfma_filter<<<1024, 256, 0, stream>>>(x, bh, esq, cnd);
        vq_refine_fused<<<NROWS / 32, 192, 0, stream>>>(x, cb, esq, cnd, xp, out);
        return;
    }
    // fp32 fallback (R12, verified 236us)
    {
        float4* et4  = (float4*)(ws + F32_ET);
        float*  esq  = ws + F32_ESQ;
        float*  xsq  = ws + F32_XSQ;
        float2* cand = (float2*)(ws + F32_CAND);

        vq_prologue_f32<<<128 + 4 + 256, 256, 0, stream>>>(x, cb, xsq, esq, et4);
        vq_main7_kernel<<<(NROWS / 8) * 4 / 4, 256, 0, stream>>>(x, et4, esq, xsq, cand);
        vq_reduce_kernel<<<NROWS / 256, 256, 0, stream>>>(cand, out);
    }
}